// Round 4
// baseline (102.042 us; speedup 1.0000x reference)
//
#include <hip/hip_runtime.h>
#include <hip/hip_bf16.h>

// Shapes: x,gn (8,128,64) f32; fb (1,128,32768) f32; resonance (64,128) f32.
// out (8,1,32768) f32.
// r[b,c,f] = sum_rr softmax(x+gn)[b,c,rr] * res[rr,f]
// out[b,s] = (1/128) * sum_c lerp(r[b,c,:], s) * fb[c,s]
//
// Single fused kernel: phase 1 (softmax+matvec -> rT in d_ws), device-wide
// barrier (atomic counter in d_ws, reset each call via hipMemsetAsync),
// phase 2 (interp + fb dot + band mean). 512 blocks x 256 thr = 2 blocks/CU;
// co-residency capacity >= 8 blocks/CU, so all blocks are resident.

#define BATCH 8
#define BANDS 128
#define RES 64
#define NF 128
#define NS 32768
#define NBC (BATCH * BANDS)   // 1024
#define NBLK 512

__global__ __launch_bounds__(256) void fused(const float* __restrict__ x,
                                             const float* __restrict__ gn,
                                             const float* __restrict__ fb,
                                             const float* __restrict__ res,
                                             float* __restrict__ out,
                                             unsigned int* __restrict__ ctr,
                                             float* __restrict__ rT) {
    const int k    = blockIdx.x;      // segment 0..511 (64 samples each)
    const int tid  = threadIdx.x;     // 0..255
    const int wave = tid >> 6;
    const int lane = tid & 63;

    // ---------- Phase 1: waves 0,1 each own one bc row (2k, 2k+1) ----------
    if (wave < 2) {
        const int bc = 2 * k + wave;
        float v = x[bc * RES + lane] + gn[bc * RES + lane];
        float m = v;
        #pragma unroll
        for (int off = 32; off > 0; off >>= 1)
            m = fmaxf(m, __shfl_xor(m, off));
        const float e = expf(v - m);
        float ssum = e;
        #pragma unroll
        for (int off = 32; off > 0; off >>= 1)
            ssum += __shfl_xor(ssum, off);
        const float g = e / ssum;

        // frames f = lane and lane+64; g[rr] broadcast via shuffle
        float r0 = 0.f, r1 = 0.f;
        #pragma unroll 8
        for (int rr = 0; rr < RES; ++rr) {
            const float gg = __shfl(g, rr);
            r0 = fmaf(gg, res[rr * NF + lane], r0);
            r1 = fmaf(gg, res[rr * NF + lane + 64], r1);
        }
        rT[lane * NBC + bc]        = r0;
        rT[(lane + 64) * NBC + bc] = r1;
    }

    // ---------- Grid barrier (device scope) ----------
    __syncthreads();
    if (tid == 0) {
        __threadfence();   // release rT stores device-wide
        __hip_atomic_fetch_add(ctr, 1u, __ATOMIC_ACQ_REL, __HIP_MEMORY_SCOPE_AGENT);
        long spins = 0;
        while (__hip_atomic_load(ctr, __ATOMIC_ACQUIRE, __HIP_MEMORY_SCOPE_AGENT) < NBLK) {
            __builtin_amdgcn_s_sleep(2);
            if (++spins > (1L << 24)) break;   // failsafe: wrong > hung
        }
    }
    __syncthreads();
    __threadfence();   // acquire: invalidate caches before reading rT

    // ---------- Phase 2: samples [64k, 64k+63], all 8 batches ----------
    __shared__ float rlo_s[NBC];
    __shared__ float dd_s[NBC];

    float pos0 = ((float)(k * 64) + 0.5f) * (1.0f / 256.0f) - 0.5f;
    pos0 = fminf(fmaxf(pos0, 0.0f), (float)(NF - 1));
    const int lo0 = (int)floorf(pos0);         // block-uniform (64-sample span)
    const int f1  = min(lo0 + 1, NF - 1);

    for (int i = tid; i < NBC; i += 256) {
        const float a = rT[lo0 * NBC + i];
        const float b = rT[f1  * NBC + i];
        rlo_s[i] = a;
        dd_s[i]  = b - a;
    }
    __syncthreads();

    const int t = lane;
    const int s = k * 64 + t;
    float pos = ((float)s + 0.5f) * (1.0f / 256.0f) - 0.5f;
    pos = fminf(fmaxf(pos, 0.0f), (float)(NF - 1));
    const float w = pos - (float)lo0;

    const int b0 = wave * 2;
    const float* __restrict__ rl0 = &rlo_s[(b0 + 0) * BANDS];
    const float* __restrict__ rl1 = &rlo_s[(b0 + 1) * BANDS];
    const float* __restrict__ dp0 = &dd_s[(b0 + 0) * BANDS];
    const float* __restrict__ dp1 = &dd_s[(b0 + 1) * BANDS];

    float acc0 = 0.f, acc1 = 0.f;
    #pragma unroll 8
    for (int c = 0; c < BANDS; c += 4) {
        const float f0  = fb[(c + 0) * NS + s];
        const float f1v = fb[(c + 1) * NS + s];
        const float f2  = fb[(c + 2) * NS + s];
        const float f3  = fb[(c + 3) * NS + s];

        const float4 r0 = *(const float4*)&rl0[c];
        const float4 d0 = *(const float4*)&dp0[c];
        acc0 = fmaf(f0,  fmaf(w, d0.x, r0.x), acc0);
        acc0 = fmaf(f1v, fmaf(w, d0.y, r0.y), acc0);
        acc0 = fmaf(f2,  fmaf(w, d0.z, r0.z), acc0);
        acc0 = fmaf(f3,  fmaf(w, d0.w, r0.w), acc0);

        const float4 r1 = *(const float4*)&rl1[c];
        const float4 d1 = *(const float4*)&dp1[c];
        acc1 = fmaf(f0,  fmaf(w, d1.x, r1.x), acc1);
        acc1 = fmaf(f1v, fmaf(w, d1.y, r1.y), acc1);
        acc1 = fmaf(f2,  fmaf(w, d1.z, r1.z), acc1);
        acc1 = fmaf(f3,  fmaf(w, d1.w, r1.w), acc1);
    }

    out[(b0 + 0) * NS + s] = acc0 * (1.0f / (float)BANDS);
    out[(b0 + 1) * NS + s] = acc1 * (1.0f / (float)BANDS);
}

extern "C" void kernel_launch(void* const* d_in, const int* in_sizes, int n_in,
                              void* d_out, int out_size, void* d_ws, size_t ws_size,
                              hipStream_t stream) {
    const float* x   = (const float*)d_in[0];
    const float* gn  = (const float*)d_in[1];
    const float* fb  = (const float*)d_in[2];
    const float* res = (const float*)d_in[3];
    float* out = (float*)d_out;

    unsigned int* ctr = (unsigned int*)d_ws;
    float* rT = (float*)((char*)d_ws + 256);   // 512 KB of the 256 MB ws

    (void)hipMemsetAsync(d_ws, 0, 4, stream);  // reset barrier counter (capturable)
    fused<<<NBLK, 256, 0, stream>>>(x, gn, fb, res, out, ctr, rT);
}

// Round 5
// 32.465 us; speedup vs baseline: 3.1431x; 3.1431x over previous
//
#include <hip/hip_runtime.h>
#include <hip/hip_bf16.h>

// Shapes: x,gn (8,128,64) f32; fb (1,128,32768) f32; resonance (64,128) f32.
// out (8,1,32768) f32.
// r[b,c,f] = sum_rr softmax(x+gn)[b,c,rr] * res[rr,f]
// out[b,s] = (1/128) * sum_c lerp(r[b,c,:], s) * fb[c,s]
//
// Single kernel, NO grid barrier (R4 showed device-scope fences cost ~90us on
// gfx950: per-XCD L2 writeback/invalidate storms). Instead each block
// redundantly recomputes the softmax+matvec it needs: for a 128-sample
// segment floor(pos) is exactly block-uniform (crossings at s=256m+127.5 are
// 128-aligned boundaries), so only 2 frames of r are needed -> thread i
// recomputes row i's softmax in registers (~512KB x+gn re-read per block,
// L2-served) and dots with 2 staged res columns. Block-local syncs only.

#define BATCH 8
#define BANDS 128
#define RES 64
#define NF 128
#define NS 32768
#define NBC (BATCH * BANDS)   // 1024
#define SEG 128               // samples per block
#define NBLK (NS / SEG)       // 256 blocks = 1 per CU
#define NTHR 1024

__global__ __launch_bounds__(NTHR, 4) void fused(const float* __restrict__ x,
                                                 const float* __restrict__ gn,
                                                 const float* __restrict__ fb,
                                                 const float* __restrict__ res,
                                                 float* __restrict__ out) {
    const int k   = blockIdx.x;      // segment 0..255
    const int tid = threadIdx.x;     // 0..1023

    __shared__ float resc0[RES];
    __shared__ float resc1[RES];
    __shared__ float r_s[NBC];
    __shared__ float dd_s[NBC];

    // block-uniform frame pair
    float pos0 = ((float)(k * SEG) + 0.5f) * (1.0f / 256.0f) - 0.5f;
    pos0 = fminf(fmaxf(pos0, 0.0f), (float)(NF - 1));
    const int f0 = (int)floorf(pos0);
    const int f1 = min(f0 + 1, NF - 1);

    if (tid < RES) {
        resc0[tid] = res[tid * NF + f0];
        resc1[tid] = res[tid * NF + f1];
    }
    __syncthreads();

    // ---- Prologue: thread tid owns softmax row bc = tid (fully in regs) ----
    float v[RES];
    {
        const float4* __restrict__ x4 = (const float4*)(x + tid * RES);
        const float4* __restrict__ g4 = (const float4*)(gn + tid * RES);
        #pragma unroll
        for (int j = 0; j < RES / 4; ++j) {
            const float4 a = x4[j];
            const float4 b = g4[j];
            v[4 * j + 0] = a.x + b.x;
            v[4 * j + 1] = a.y + b.y;
            v[4 * j + 2] = a.z + b.z;
            v[4 * j + 3] = a.w + b.w;
        }
    }
    float m = v[0];
    #pragma unroll
    for (int t = 1; t < RES; ++t) m = fmaxf(m, v[t]);
    float sum = 0.f;
    #pragma unroll
    for (int t = 0; t < RES; ++t) { v[t] = __expf(v[t] - m); sum += v[t]; }
    const float inv = 1.0f / sum;

    float r0 = 0.f, r1 = 0.f;
    {
        const float4* __restrict__ c0q = (const float4*)resc0;
        const float4* __restrict__ c1q = (const float4*)resc1;
        #pragma unroll
        for (int j = 0; j < RES / 4; ++j) {
            const float4 c0 = c0q[j];
            const float4 c1 = c1q[j];
            r0 = fmaf(v[4*j+0], c0.x, r0);  r1 = fmaf(v[4*j+0], c1.x, r1);
            r0 = fmaf(v[4*j+1], c0.y, r0);  r1 = fmaf(v[4*j+1], c1.y, r1);
            r0 = fmaf(v[4*j+2], c0.z, r0);  r1 = fmaf(v[4*j+2], c1.z, r1);
            r0 = fmaf(v[4*j+3], c0.w, r0);  r1 = fmaf(v[4*j+3], c1.w, r1);
        }
    }
    r0 *= inv;
    r1 *= inv;
    r_s[tid]  = r0;
    dd_s[tid] = r1 - r0;
    __syncthreads();

    // ---- Main: thread = (batch, sample) pair ----
    const int b  = tid >> 7;        // 0..7
    const int sl = tid & 127;       // 0..127
    const int s  = k * SEG + sl;

    float pos = ((float)s + 0.5f) * (1.0f / 256.0f) - 0.5f;
    pos = fminf(fmaxf(pos, 0.0f), (float)(NF - 1));
    const float w = pos - (float)f0;   // f0 block-uniform by construction

    const float* __restrict__ rl = &r_s[b * BANDS];
    const float* __restrict__ dp = &dd_s[b * BANDS];

    float acc = 0.f;
    #pragma unroll 8
    for (int c = 0; c < BANDS; c += 4) {
        const float fb0 = fb[(c + 0) * NS + s];
        const float fb1 = fb[(c + 1) * NS + s];
        const float fb2 = fb[(c + 2) * NS + s];
        const float fb3 = fb[(c + 3) * NS + s];
        const float4 rr = *(const float4*)&rl[c];
        const float4 dd = *(const float4*)&dp[c];
        acc = fmaf(fb0, fmaf(w, dd.x, rr.x), acc);
        acc = fmaf(fb1, fmaf(w, dd.y, rr.y), acc);
        acc = fmaf(fb2, fmaf(w, dd.z, rr.z), acc);
        acc = fmaf(fb3, fmaf(w, dd.w, rr.w), acc);
    }

    out[b * NS + s] = acc * (1.0f / (float)BANDS);
}

extern "C" void kernel_launch(void* const* d_in, const int* in_sizes, int n_in,
                              void* d_out, int out_size, void* d_ws, size_t ws_size,
                              hipStream_t stream) {
    const float* x   = (const float*)d_in[0];
    const float* gn  = (const float*)d_in[1];
    const float* fb  = (const float*)d_in[2];
    const float* res = (const float*)d_in[3];
    float* out = (float*)d_out;

    fused<<<NBLK, NTHR, 0, stream>>>(x, gn, fb, res, out);
}

// Round 6
// 17.912 us; speedup vs baseline: 5.6968x; 1.8125x over previous
//
#include <hip/hip_runtime.h>
#include <hip/hip_bf16.h>

// Shapes: x,gn (8,128,64) f32; fb (1,128,32768) f32; resonance (64,128) f32.
// out (8,1,32768) f32.
// r[b,c,f] = sum_rr softmax(x+gn)[b,c,rr] * res[rr,f]
// out[b,s] = (1/128) * sum_c lerp(r[b,c,:], s) * fb[c,s]
//
// Two kernels (R4 grid-barrier = 90us cache storms; R5 fused-redundant =
// VGPR spills + serialized 134MB re-read -- both dead ends).
// kB occupancy doubled vs R3: SEG=32, 1024 blocks, 4 blk/CU, 4 waves/SIMD.

#define BATCH 8
#define BANDS 128
#define RES 64
#define NF 128
#define NS 32768
#define NBC (BATCH * BANDS)   // 1024
#define SEG 32
#define NBLKB (NS / SEG)      // 1024

// ---------------- Kernel A: softmax + matvec -> rT[f][b*128+c] ----------------
__global__ __launch_bounds__(64) void kA(const float* __restrict__ x,
                                         const float* __restrict__ gn,
                                         const float* __restrict__ res,
                                         float* __restrict__ rT) {
    const int bc = blockIdx.x;        // b*128 + c, 0..1023
    const int t  = threadIdx.x;       // 0..63 (one full wave)

    float v = x[bc * RES + t] + gn[bc * RES + t];

    float m = v;
    #pragma unroll
    for (int off = 32; off > 0; off >>= 1)
        m = fmaxf(m, __shfl_xor(m, off));
    const float e = expf(v - m);
    float ssum = e;
    #pragma unroll
    for (int off = 32; off > 0; off >>= 1)
        ssum += __shfl_xor(ssum, off);
    const float g = e / ssum;

    __shared__ float gs[RES];
    gs[t] = g;
    __syncthreads();

    float r0 = 0.f, r1 = 0.f;
    #pragma unroll 4
    for (int rr = 0; rr < RES; ++rr) {
        const float gg = gs[rr];
        r0 = fmaf(gg, res[rr * NF + t], r0);
        r1 = fmaf(gg, res[rr * NF + t + 64], r1);
    }
    rT[t * NBC + bc]        = r0;
    rT[(t + 64) * NBC + bc] = r1;
}

// ---------------- Kernel B: interp + fb dot + band mean ----------------
// Block k: samples [32k, 32k+31], all 8 batches. thread = (b, sl):
// b = tid>>5, sl = tid&31. floor(pos) is block-uniform (crossings at
// s = 256m+127.5 are 32-aligned boundaries) -> stage rlo + dd in LDS.
// Half-waves read identical fb bytes (merge to one 128B transaction);
// LDS reads are 2-address broadcasts (2-way aliasing is free).
__global__ __launch_bounds__(256) void kB(const float* __restrict__ fb,
                                          const float* __restrict__ rT,
                                          float* __restrict__ out) {
    const int k   = blockIdx.x;       // 0..1023
    const int tid = threadIdx.x;      // 0..255
    const int b   = tid >> 5;         // 0..7
    const int sl  = tid & 31;         // 0..31
    const int s   = k * SEG + sl;

    __shared__ float rlo_s[NBC];
    __shared__ float dd_s[NBC];

    float pos0 = ((float)(k * SEG) + 0.5f) * (1.0f / 256.0f) - 0.5f;
    pos0 = fminf(fmaxf(pos0, 0.0f), (float)(NF - 1));
    const int lo0 = (int)floorf(pos0);        // block-uniform
    const int f1  = min(lo0 + 1, NF - 1);

    for (int i = tid; i < NBC; i += 256) {
        const float a  = rT[lo0 * NBC + i];
        const float bb = rT[f1  * NBC + i];
        rlo_s[i] = a;
        dd_s[i]  = bb - a;
    }
    __syncthreads();

    float pos = ((float)s + 0.5f) * (1.0f / 256.0f) - 0.5f;
    pos = fminf(fmaxf(pos, 0.0f), (float)(NF - 1));
    const float w = pos - (float)lo0;

    const float* __restrict__ rl = &rlo_s[b * BANDS];
    const float* __restrict__ dp = &dd_s[b * BANDS];

    float acc = 0.f;
    #pragma unroll 8
    for (int c = 0; c < BANDS; c += 4) {
        const float fb0 = fb[(c + 0) * NS + s];
        const float fb1 = fb[(c + 1) * NS + s];
        const float fb2 = fb[(c + 2) * NS + s];
        const float fb3 = fb[(c + 3) * NS + s];
        const float4 rr = *(const float4*)&rl[c];
        const float4 dd = *(const float4*)&dp[c];
        acc = fmaf(fb0, fmaf(w, dd.x, rr.x), acc);
        acc = fmaf(fb1, fmaf(w, dd.y, rr.y), acc);
        acc = fmaf(fb2, fmaf(w, dd.z, rr.z), acc);
        acc = fmaf(fb3, fmaf(w, dd.w, rr.w), acc);
    }

    out[b * NS + s] = acc * (1.0f / (float)BANDS);
}

extern "C" void kernel_launch(void* const* d_in, const int* in_sizes, int n_in,
                              void* d_out, int out_size, void* d_ws, size_t ws_size,
                              hipStream_t stream) {
    const float* x   = (const float*)d_in[0];
    const float* gn  = (const float*)d_in[1];
    const float* fb  = (const float*)d_in[2];
    const float* res = (const float*)d_in[3];
    float* out = (float*)d_out;
    float* rT  = (float*)d_ws;   // NF * NBC floats = 512 KB

    kA<<<NBC, 64, 0, stream>>>(x, gn, res, rT);
    kB<<<NBLKB, 256, 0, stream>>>(fb, rT, out);
}